// Round 2
// 103.062 us; speedup vs baseline: 1.0222x; 1.0222x over previous
//
#include <hip/hip_runtime.h>
#include <hip/hip_fp16.h>

// Problem constants (from reference)
#define BB 8
#define NN 10000
#define TT 2000
#define SS 12
#define HH 128
#define TOTAL_E (BB * NN)           // 80000
#define COEF 1.2615662610100802f    // GAUSS_NORM / sqrt(BIN_SIGMA)

// Bucket sort: lambda ~ 5 electrons/bin; P(bin > 32) ~ 1e-16.
#define CAP 32
#define REC_W 8                     // dwords per record (32 B): z, coef, resp[12] f16

// Gather tiling
#define TB 20                       // ticks per block
#define NB 26                       // bins staged = TB + 6
#define SZP 33                      // padded stride: bank = (bb+u)%32, conflict-free
#define SRP 198                     // CAP*6+6: bank shift 6/bb, conflict-free

// Workspace layout (bytes)
#define WS_CURSOR 0                 // 8*2000 u32 = 64 KB
#define WS_REC    65536             // 8*2000*32 rec * 32 B = 16.4 MB

typedef _Float16 half8 __attribute__((ext_vector_type(8)));
typedef float f32x4 __attribute__((ext_vector_type(4)));

// Wave-level LDS fence: compiler memory clobber (no reordering of DS ops) +
// wave_barrier (no cross-lane motion). Hardware DS pipe is in-order per wave,
// so no s_waitcnt / s_barrier is needed for wave-private LDS dataflow.
#define WAVE_LDS_FENCE() do { \
    __asm__ volatile("" ::: "memory"); \
    __builtin_amdgcn_wave_barrier(); \
    __asm__ volatile("" ::: "memory"); \
} while (0)

// Swizzled LDS addressing for [row][128 halves] tiles: 16 chunks of 8 halves;
// phys_chunk = chunk ^ (row & 7).
__device__ __forceinline__ int swz(int row, int chunk) {
    return row * 128 + ((chunk ^ (row & 7)) * 8);
}

// RTE pack of two f32 -> one dword of two f16 (v_cvt_f16_f32 x2 + pack).
__device__ __forceinline__ unsigned int pack2(float a, float b) {
    _Float16 ha = (_Float16)a, hb = (_Float16)b;
    unsigned short ua = __builtin_bit_cast(unsigned short, ha);
    unsigned short ub = __builtin_bit_cast(unsigned short, hb);
    return (unsigned int)ua | ((unsigned int)ub << 16);
}

// ---------------- K1: transposed-output MFMA MLP, zero block barriers in loop ----
// Operand-swap trick: mfma(W^T_frag, x^T_frag) computes the transposed output, so
// each lane holds 4 CONSECUTIVE channels of ONE electron -> packed b64 h-writeback
// and a shfl-free record epilogue. All h LDS traffic is wave-private (wave w only
// touches rows [16w,16w+16)), so __syncthreads is replaced by wave-level fences
// (DS ops within a wave complete in order).
__global__ __launch_bounds__(256) void mlp_kernel(
    const float* __restrict__ de,    // (B,N,3)
    const float* __restrict__ mask,  // (B,N)
    const float* __restrict__ W1, const float* __restrict__ b1,
    const float* __restrict__ W2, const float* __restrict__ b2,
    const float* __restrict__ W3, const float* __restrict__ b3,
    unsigned int* __restrict__ cursor,
    float* __restrict__ rec)
{
    __shared__ _Float16 sW2T[HH * 128];   // [n][k] transposed, swizzled, 32 KB
    __shared__ _Float16 sh[64 * 128];     // h scratch, wave-private rows, 16 KB

    const int tid = threadIdx.x;
    const int wave = tid >> 6;
    const int lane = tid & 63;
    const int q = lane >> 4;      // quad 0..3
    const int i = lane & 15;      // tile row/col index

    // ---- stage W2^T -> LDS (f16, swizzled, b128 writes) ----
    {
        const int n = tid >> 1;
        const int kh = (tid & 1) * 8;
        #pragma unroll
        for (int c8 = 0; c8 < 8; ++c8) {
            const int c = kh + c8;
            half8 v;
            #pragma unroll
            for (int j = 0; j < 8; ++j)
                v[j] = (_Float16)W2[(c * 8 + j) * HH + n];   // W2[k][n]
            *(half8*)(sW2T + swz(n, c)) = v;
        }
    }

    // ---- loop-invariant fragments / biases ----
    // W1^T as A-operand: lane holds A[row=n=nt*16+i][k=q*8+j]; bias folded at k=3.
    half8 bW1[8];
    #pragma unroll
    for (int nt = 0; nt < 8; ++nt) {
        half8 f = {};
        if (q == 0) {
            const int n = nt * 16 + i;
            f[0] = (_Float16)W1[n];
            f[1] = (_Float16)W1[HH + n];
            f[2] = (_Float16)W1[2 * HH + n];
            f[3] = (_Float16)b1[n];          // bias via k=3 (x^T provides 1.0)
        }
        bW1[nt] = f;
    }
    // W3^T as A-operand: lane holds A[row=s=i][k=c*32+q*8+j] (rows >= 12 zero).
    half8 bW3[4];
    #pragma unroll
    for (int c = 0; c < 4; ++c) {
        half8 f = {};
        if (i < SS) {
            #pragma unroll
            for (int j = 0; j < 8; ++j)
                f[j] = (_Float16)W3[(c * 32 + q * 8 + j) * SS + i];
        }
        bW3[c] = f;
    }
    // f32 biases for the channels this lane now produces: n = nt*16 + q*4 + r.
    float b2f[8][4];
    #pragma unroll
    for (int nt = 0; nt < 8; ++nt)
        #pragma unroll
        for (int r = 0; r < 4; ++r)
            b2f[nt][r] = b2[nt * 16 + q * 4 + r];
    float b3f[4];
    #pragma unroll
    for (int r = 0; r < 4; ++r)
        b3f[r] = (q < 3) ? b3[q * 4 + r] : 0.f;

    __syncthreads();  // sW2T staged (only block-wide barrier in the kernel)

    const int mrow = wave * 16;
    const int hrow = mrow + i;            // this lane's electron row in sh

    for (int base = blockIdx.x * 64; base < TOTAL_E; base += gridDim.x * 64) {
        const int m_glob = base + mrow + i;
        const int bi = m_glob / NN;
        const float x0 = de[m_glob * 3 + 0];
        const float x1 = de[m_glob * 3 + 1];
        const float x2 = de[m_glob * 3 + 2];   // = z
        const float coef = mask[m_glob] * COEF;

        half8 aX = {};
        if (q == 0) {
            aX[0] = (_Float16)x0; aX[1] = (_Float16)x1;
            aX[2] = (_Float16)x2; aX[3] = (_Float16)1.f;   // bias lane
        }

        // fence: this pass's h1 writes must not cross prior pass's h2 reads
        WAVE_LDS_FENCE();

        // ---- S1: h1^T = relu(W1^T x^T + b1); lane -> electron i, ch nt*16+q*4+r ----
        #pragma unroll
        for (int nt = 0; nt < 8; ++nt) {
            f32x4 a = {};
            a = __builtin_amdgcn_mfma_f32_16x16x32_f16(bW1[nt], aX, a, 0, 0, 0);
            const unsigned int lo = pack2(fmaxf(a[0], 0.f), fmaxf(a[1], 0.f));
            const unsigned int hi = pack2(fmaxf(a[2], 0.f), fmaxf(a[3], 0.f));
            const int chunk = nt * 2 + (q >> 1);
            uint2 u; u.x = lo; u.y = hi;
            *(uint2*)(sh + hrow * 128 + ((chunk ^ (i & 7)) * 8) + (q & 1) * 4) = u;
        }
        WAVE_LDS_FENCE();   // h1 writes before h1 reads (in-order DS pipe)

        // ---- S2: h2^T = relu(W2^T h1^T + b2) ----
        half8 aH[4];
        #pragma unroll
        for (int c = 0; c < 4; ++c)
            aH[c] = *(const half8*)(sh + swz(hrow, c * 4 + q));

        f32x4 acc2[8];
        #pragma unroll
        for (int nt = 0; nt < 8; ++nt) acc2[nt] = (f32x4){};
        #pragma unroll
        for (int c = 0; c < 4; ++c) {
            #pragma unroll
            for (int nt = 0; nt < 8; ++nt) {
                const half8 bf = *(const half8*)(sW2T + swz(nt * 16 + i, c * 4 + q));
                acc2[nt] = __builtin_amdgcn_mfma_f32_16x16x32_f16(bf, aH[c], acc2[nt], 0, 0, 0);
            }
        }
        WAVE_LDS_FENCE();   // h1 reads before h2 overwrites

        #pragma unroll
        for (int nt = 0; nt < 8; ++nt) {
            const unsigned int lo = pack2(fmaxf(acc2[nt][0] + b2f[nt][0], 0.f),
                                          fmaxf(acc2[nt][1] + b2f[nt][1], 0.f));
            const unsigned int hi = pack2(fmaxf(acc2[nt][2] + b2f[nt][2], 0.f),
                                          fmaxf(acc2[nt][3] + b2f[nt][3], 0.f));
            const int chunk = nt * 2 + (q >> 1);
            uint2 u; u.x = lo; u.y = hi;
            *(uint2*)(sh + hrow * 128 + ((chunk ^ (i & 7)) * 8) + (q & 1) * 4) = u;
        }
        WAVE_LDS_FENCE();   // h2 writes before h2 reads

        // ---- S3: resp^T = W3^T h2^T + b3; lane -> electron i, s = q*4+r ----
        f32x4 acc3 = {};
        #pragma unroll
        for (int c = 0; c < 4; ++c) {
            const half8 a2 = *(const half8*)(sh + swz(hrow, c * 4 + q));
            acc3 = __builtin_amdgcn_mfma_f32_16x16x32_f16(bW3[c], a2, acc3, 0, 0, 0);
        }

        // ---- claim bucket slot (lanes 0..15 = the wave's 16 electrons) ----
        unsigned int ridx = 0;
        if (lane < 16) {
            int bin = (int)x2;
            bin = bin < 0 ? 0 : (bin > TT - 1 ? TT - 1 : bin);
            unsigned int slot = atomicAdd(&cursor[bi * TT + bin], 1u);
            if (slot >= CAP) slot = CAP - 1;   // statistically unreachable
            ridx = (unsigned int)(bi * TT + bin) * CAP + slot;
        }
        const unsigned int rx = (unsigned int)__shfl((int)ridx, i);

        // ---- record write: electron i's 32 B record written by its 4 q-lanes ----
        // q<3: resp dwords 2+2q, 3+2q (s = q*4..q*4+3); q==3: words 0,1 = z, coef.
        float2 v;
        int off;
        if (q == 3) {
            v.x = x2; v.y = coef; off = 0;
        } else {
            v.x = __uint_as_float(pack2(acc3[0] + b3f[0], acc3[1] + b3f[1]));
            v.y = __uint_as_float(pack2(acc3[2] + b3f[2], acc3[3] + b3f[3]));
            off = 2 + 2 * q;
        }
        *(float2*)(rec + (size_t)rx * REC_W + off) = v;
    }
}

// ---------------- K2: block-cooperative gather ----------------
// Block = (b, 20-tick chunk). Stage 26 bins of records into LDS (coalesced,
// read once per block), then thread (t,s) sums its 7-bin window from LDS.
// Padded LDS strides (33 / 198) kill the former ~6-way bank conflicts.
__global__ __launch_bounds__(256) void gather_kernel(
    const unsigned int* __restrict__ cursor,  // per-bin counts
    const float* __restrict__ rec,
    float* __restrict__ out)                  // (B, S, T)
{
    __shared__ float sz[NB * SZP];
    __shared__ float sc[NB * SZP];
    __shared__ unsigned int srsp[NB * SRP];   // resp as 6 half2 words per record
    __shared__ unsigned int lcnt[NB];

    const int b = blockIdx.x / (TT / TB);
    const int t0 = (blockIdx.x % (TT / TB)) * TB;
    const int tid = threadIdx.x;
    const int wv = tid >> 6;
    const int ln = tid & 63;

    // ---- phase 1: stage bins [t0-3, t0+TB+2] ----
    for (int bb = wv; bb < NB; bb += 4) {
        const int g = t0 - 3 + bb;
        unsigned int c = 0;
        if (g >= 0 && g < TT) {
            c = cursor[b * TT + g];
            if (c > CAP) c = CAP;
        }
        if (ln == 0) lcnt[bb] = c;
        const float* src = rec + (size_t)(b * TT + g) * CAP * REC_W;
        for (unsigned int idx = ln; idx < c * 8u; idx += 64) {
            const unsigned int slot = idx >> 3;
            const unsigned int w = idx & 7;
            const float v = src[slot * REC_W + w];
            if (w == 0)      sz[bb * SZP + slot] = v;
            else if (w == 1) sc[bb * SZP + slot] = v;
            else             srsp[bb * SRP + slot * 6u + (w - 2u)] = __float_as_uint(v);
        }
    }
    __syncthreads();

    // ---- phase 2: thread = (t_local, s) ----
    const int t_l = tid / SS;
    const int s = tid - t_l * SS;
    if (t_l >= TB) return;
    const int t = t0 + t_l;
    const float tf = (float)t;
    float acc = 0.f;
    #pragma unroll
    for (int o = 0; o < 7; ++o) {
        const int bb = t_l + o;           // bin g = t-3+o
        const unsigned int c = lcnt[bb];
        const int zb = bb * SZP;
        const int rb = bb * SRP;
        for (unsigned int u = 0; u < c; ++u) {
            const float z = sz[zb + u];
            const float cc = sc[zb + u];
            const float d = tf - z;
            const unsigned int rw = srsp[rb + u * 6u + (unsigned)(s >> 1)];
            const __half2 h2 = *(const __half2*)&rw;
            const float rv = (s & 1) ? __half2float(h2.y) : __half2float(h2.x);
            acc = fmaf(__expf(-5.0f * d * d) * cc, rv, acc);
        }
    }
    out[(b * SS + s) * TT + t] = acc;
}

extern "C" void kernel_launch(void* const* d_in, const int* in_sizes, int n_in,
                              void* d_out, int out_size, void* d_ws, size_t ws_size,
                              hipStream_t stream) {
    const float* de   = (const float*)d_in[0];
    const float* mask = (const float*)d_in[1];
    const float* W1   = (const float*)d_in[2];
    const float* b1   = (const float*)d_in[3];
    const float* W2   = (const float*)d_in[4];
    const float* b2   = (const float*)d_in[5];
    const float* W3   = (const float*)d_in[6];
    const float* b3   = (const float*)d_in[7];
    float* out = (float*)d_out;

    char* ws = (char*)d_ws;
    unsigned int* cursor = (unsigned int*)(ws + WS_CURSOR);
    float*        rec    = (float*)(ws + WS_REC);

    // cursor doubles as histogram; must start at zero every call.
    hipMemsetAsync(cursor, 0, BB * TT * sizeof(unsigned int), stream);

    mlp_kernel<<<625, 256, 0, stream>>>(de, mask, W1, b1, W2, b2, W3, b3,
                                        cursor, rec);
    gather_kernel<<<BB * (TT / TB), 256, 0, stream>>>(cursor, rec, out);
}